// Round 1
// baseline (229.038 us; speedup 1.0000x reference)
//
#include <hip/hip_runtime.h>

// GraphSAGE 2-layer + linear head, N=50000, E=600000, C=128 everywhere.
// R10: (a) FUSE gemm2+gemm3 -> gemm23: x1 A-frags reused in-register for the
//      head (identical lane layout), x2 never round-trips through global
//      (C->A transpose via XOR-swizzled 32KB LDS tile reusing dead Wt2 LDS;
//      b128 reads conflict-free), Wt3 B-frags streamed from global (L2
//      broadcast). Eliminates x2h entirely + 1 launch + ~38MB L2/L3 traffic.
//      (b) FOLD scan_block_kernel into scatter/bucket: per-thread ghist row
//      sum + shfl 256-scan reconstructs the global prefix. -1 launch.
// R9 ledger (keep): slice-agg +14..20 REGRESSED vs R3 prefetch-all agg;
//      ILP-depth neutral, fp8 bytes neutral, XCD-slice negative => no more
//      agg bets without per-kernel data. v2 64KB gemm beats col-split by 4.

typedef _Float16 f16;
typedef unsigned int u32;
typedef __attribute__((ext_vector_type(4))) _Float16 f16x4;
typedef __attribute__((ext_vector_type(8))) _Float16 f16x8;
typedef __attribute__((ext_vector_type(4))) float f32x4;

#define RNB 128   // radix blocks (256 bins x 128 = 32768 hist entries)

// ---- prep: [0,cb) convert x -> f16 | [cb,cb+wb) weights | rest: radix hist
// weights k-chunked transposed, 3 tables contiguous (32768 f16 each):
// wt[w][(chunk*128 + n)*8 + j] = W_w[k=chunk*8+j][n], W = [WA;WB] stacked.
__global__ void prep_kernel(const float* __restrict__ x, f16* __restrict__ xh, int n4,
                            const int* __restrict__ ei, int* __restrict__ ghist, int E,
                            const float* __restrict__ W1l, const float* __restrict__ W1r,
                            const float* __restrict__ W2l, const float* __restrict__ W2r,
                            const float* __restrict__ Wlin, f16* __restrict__ wt,
                            int cb, int wb) {
  int b = blockIdx.x;
  if (b < cb) {
    int i = b * 256 + threadIdx.x;
    if (i < n4) {
      const float4 v = ((const float4*)x)[i];
      f16x4 h = { (f16)v.x, (f16)v.y, (f16)v.z, (f16)v.w };
      ((f16x4*)xh)[i] = h;
    }
  } else if (b < cb + wb) {
    int tid = (b - cb) * 256 + threadIdx.x;   // 0 .. 3*32768
    int w = tid >> 15, idx = tid & 32767;
    int j = idx & 7, n = (idx >> 3) & 127, chunk = idx >> 10;
    int k = chunk * 8 + j;
    float v;
    if (w == 0) v = (k < 128) ? W1l[k * 128 + n] : W1r[(k - 128) * 128 + n];
    else if (w == 1) v = (k < 128) ? W2l[k * 128 + n] : W2r[(k - 128) * 128 + n];
    else v = Wlin[k * 128 + n];
    wt[tid] = (f16)v;
  } else {
    __shared__ int h[256];
    int tid = threadIdx.x, rb = b - cb - wb;   // 0..RNB-1
    h[tid] = 0;
    __syncthreads();
    int per = (E + RNB - 1) / RNB;
    int s = rb * per, e = s + per; if (e > E) e = E;
    for (int i = s + tid; i < e; i += 256) atomicAdd(&h[ei[E + i] >> 8], 1);
    __syncthreads();
    ghist[tid * RNB + rb] = h[tid];
  }
}

// shfl-based exclusive scan over 256 threads (4 waves); one barrier.
// returns exclusive prefix of v; ws must be __shared__ int[4].
__device__ inline int block_excl_scan256(int v, int* ws) {
  int lane = threadIdx.x & 63, w = threadIdx.x >> 6;
  int incl = v;
#pragma unroll
  for (int o = 1; o < 64; o <<= 1) {
    int u = __shfl_up(incl, o);
    if (lane >= o) incl += u;
  }
  if (lane == 63) ws[w] = incl;
  __syncthreads();
  int base = 0;
#pragma unroll
  for (int i = 0; i < 4; ++i) base += (i < w) ? ws[i] : 0;
  return base + incl - v;
}

// deterministic scatter into per-(block,bin) ranges; LDS cursors only.
// Global prefix rebuilt inline from ghist (row-sum + 256-scan) — no scan kernel.
// tmp entry = (src<<8) | (dst & 255)  -- 32-bit, requires src < 2^24.
__global__ void radix_scatter(const int* __restrict__ ei, const int* __restrict__ ghist,
                              u32* __restrict__ tmp, int E) {
  __shared__ int cur[256];
  __shared__ int ws[4];
  int tid = threadIdx.x, b = blockIdx.x;
  const int* row = ghist + tid * RNB;
  int part = 0, rest = 0;
  for (int i = 0; i < b; ++i) part += row[i];          // entries of my bin in blocks < b
  for (int i = b; i < RNB; ++i) rest += row[i];
  int total = part + rest;
  int excl = block_excl_scan256(total, ws);            // entries of bins < mine
  cur[tid] = excl + part;
  __syncthreads();
  int per = (E + RNB - 1) / RNB;
  int s = b * per, e = s + per; if (e > E) e = E;
  for (int i = s + tid; i < e; i += 256) {
    int d = ei[E + i], sr = ei[i];
    int pos = atomicAdd(&cur[d >> 8], 1);              // LDS atomic
    tmp[pos] = ((u32)sr << 8) | (u32)(d & 255);
  }
}

// one block per high-byte bucket: LDS low-byte hist + scan -> off[] + srcs.
__global__ void radix_bucket(const u32* __restrict__ tmp, const int* __restrict__ ghist,
                             int* __restrict__ srcs, int* __restrict__ off,
                             int N, int E, int HB) {
  __shared__ int h[256], sc[256], cur[256];
  __shared__ int bsc[257];
  __shared__ int ws[4];
  int tid = threadIdx.x, hb = blockIdx.x;
  // rebuild global per-bin prefix from ghist
  const int* row = ghist + tid * RNB;
  int total = 0;
#pragma unroll 4
  for (int i = 0; i < RNB; ++i) total += row[i];
  int excl = block_excl_scan256(total, ws);
  bsc[tid] = excl;
  if (tid == 255) bsc[256] = E;
  h[tid] = 0;
  __syncthreads();
  int start = bsc[hb];
  int end = bsc[hb + 1];
  for (int i = start + tid; i < end; i += 256) atomicAdd(&h[tmp[i] & 255u], 1);
  __syncthreads();
  sc[tid] = h[tid];
  __syncthreads();
  for (int o = 1; o < 256; o <<= 1) {
    int u = (tid >= o) ? sc[tid - o] : 0;
    __syncthreads();
    sc[tid] += u;
    __syncthreads();
  }
  int exclb = sc[tid] - h[tid];
  int v = (hb << 8) + tid;
  if (v < N) off[v] = start + exclb;
  if (hb == 0 && tid == 0) off[N] = E;
  cur[tid] = start + exclb;
  __syncthreads();
  for (int i = start + tid; i < end; i += 256) {
    u32 p = tmp[i];
    int pos = atomicAdd(&cur[p & 255u], 1);   // LDS atomic
    srcs[pos] = (int)(p >> 8);
  }
}

// agg v3 (R3, best measured): wave = 2 nodes; lane = slot(sub) x chgroup(n15).
// Prefetch up to 24 edge indices/node, then all gathers, single drain,
// fp32 accum, cross-slot shfl reduce, f16 mean out.
#define AGG_R 6
__global__ void aggregate_kernel(const f16* __restrict__ feat, const int* __restrict__ off,
                                 const int* __restrict__ srcs, f16* __restrict__ meanf, int n) {
  int pair = (int)((blockIdx.x * blockDim.x + threadIdx.x) >> 6);
  int w0 = pair * 2;
  if (w0 >= n) return;
  int w1 = w0 + 1;
  int lane = threadIdx.x & 63;
  int sub = lane >> 4, n15 = lane & 15;
  int beg0 = off[w0], end0 = off[w0 + 1];
  int beg1 = end0;                              // CSR contiguity
  int end1 = (w1 < n) ? off[w1 + 1] : end0;
  int deg0 = end0 - beg0, deg1 = end1 - beg1;

  int s0[AGG_R], s1[AGG_R];
  bool v0[AGG_R], v1[AGG_R];
#pragma unroll
  for (int k = 0; k < AGG_R; ++k) {
    int p = 4 * k + sub;
    v0[k] = p < deg0;  s0[k] = v0[k] ? srcs[beg0 + p] : 0;
    v1[k] = p < deg1;  s1[k] = v1[k] ? srcs[beg1 + p] : 0;
  }
  f16x8 g0[AGG_R], g1[AGG_R];
#pragma unroll
  for (int k = 0; k < AGG_R; ++k) {
    if (v0[k]) g0[k] = *(const f16x8*)(feat + (size_t)s0[k] * 128 + n15 * 8);
    if (v1[k]) g1[k] = *(const f16x8*)(feat + (size_t)s1[k] * 128 + n15 * 8);
  }
  float acc0[8] = {}, acc1[8] = {};
#pragma unroll
  for (int k = 0; k < AGG_R; ++k) {
    if (v0[k]) {
#pragma unroll
      for (int j = 0; j < 8; ++j) acc0[j] += (float)g0[k][j];
    }
    if (v1[k]) {
#pragma unroll
      for (int j = 0; j < 8; ++j) acc1[j] += (float)g1[k][j];
    }
  }
  for (int e = beg0 + 4 * AGG_R; e < end0; e += 4) {   // rare deg>24 tail
    if (sub < end0 - e) {
      int s = srcs[e + sub];
      f16x8 g = *(const f16x8*)(feat + (size_t)s * 128 + n15 * 8);
#pragma unroll
      for (int j = 0; j < 8; ++j) acc0[j] += (float)g[j];
    }
  }
  for (int e = beg1 + 4 * AGG_R; e < end1; e += 4) {
    if (sub < end1 - e) {
      int s = srcs[e + sub];
      f16x8 g = *(const f16x8*)(feat + (size_t)s * 128 + n15 * 8);
#pragma unroll
      for (int j = 0; j < 8; ++j) acc1[j] += (float)g[j];
    }
  }
#pragma unroll
  for (int j = 0; j < 8; ++j) {
    acc0[j] += __shfl_xor(acc0[j], 16);
    acc0[j] += __shfl_xor(acc0[j], 32);
    acc1[j] += __shfl_xor(acc1[j], 16);
    acc1[j] += __shfl_xor(acc1[j], 32);
  }
  if (sub == 0) {
    float inv = 1.0f / fmaxf((float)deg0, 1.0f);
    f16x8 o;
#pragma unroll
    for (int j = 0; j < 8; ++j) o[j] = (f16)(acc0[j] * inv);
    *(f16x8*)(meanf + (size_t)w0 * 128 + n15 * 8) = o;
  } else if (sub == 1 && w1 < n) {
    float inv = 1.0f / fmaxf((float)deg1, 1.0f);
    f16x8 o;
#pragma unroll
    for (int j = 0; j < 8; ++j) o[j] = (f16)(acc1[j] * inv);
    *(f16x8*)(meanf + (size_t)w1 * 128 + n15 * 8) = o;
  }
}

// GEMM v2 (best measured, layer 1): Y[M,128] = act([U|V][M,256] @ W + bias);
// Wt k-chunked in 64KB LDS; 4 waves; wave = 32 rows x 128 cols.
template <bool RELU, bool OUT16>
__global__ __launch_bounds__(256, 2) void gemm_kernel(
    const f16* __restrict__ U, const f16* __restrict__ V, const f16* __restrict__ Wt,
    const float* __restrict__ bias, void* __restrict__ outp, int M) {
  __shared__ f16 ldsb[32768];   // 64 KB
  int tid = threadIdx.x;
  int wave = tid >> 6, lane = tid & 63;
  int quad = lane >> 4, n15 = lane & 15;
  int m0 = blockIdx.x * 128 + wave * 32;
  int kq = quad * 8;

  f16x8 a[2][8];
#pragma unroll
  for (int r = 0; r < 2; ++r) {
    int row = m0 + r * 16 + n15;
    int rowc = row < M ? row : M - 1;   // clamp tail loads (stores guarded)
    const f16* bu = U + (size_t)rowc * 128 + kq;
    const f16* bv = V + (size_t)rowc * 128 + kq;
#pragma unroll
    for (int kk = 0; kk < 4; ++kk) a[r][kk] = *(const f16x8*)(bu + kk * 32);
#pragma unroll
    for (int kk = 4; kk < 8; ++kk) a[r][kk] = *(const f16x8*)(bv + (kk - 4) * 32);
  }

#pragma unroll
  for (int it = 0; it < 16; ++it) {
    int idx = it * 256 + tid;
    ((f16x8*)ldsb)[idx] = ((const f16x8*)Wt)[idx];
  }
  __syncthreads();

  f32x4 acc[2][8] = {};
#pragma unroll
  for (int kk = 0; kk < 8; ++kk) {
#pragma unroll
    for (int t = 0; t < 8; ++t) {
      f16x8 b = ((const f16x8*)ldsb)[(kk * 4 + quad) * 128 + t * 16 + n15];
#pragma unroll
      for (int r = 0; r < 2; ++r)
        acc[r][t] = __builtin_amdgcn_mfma_f32_16x16x32_f16(a[r][kk], b, acc[r][t], 0, 0, 0);
    }
  }

  int rbase0 = m0 + quad * 4;
#pragma unroll
  for (int t = 0; t < 8; ++t) {
    float bv = bias[t * 16 + n15];
#pragma unroll
    for (int r = 0; r < 2; ++r) {
#pragma unroll
      for (int i = 0; i < 4; ++i) {
        int row = rbase0 + r * 16 + i;
        if (row < M) {
          float v = acc[r][t][i] + bv;
          if (RELU) v = fmaxf(v, 0.f);
          size_t idx = (size_t)row * 128 + t * 16 + n15;
          if (OUT16) ((f16*)outp)[idx] = (f16)v;
          else       ((float*)outp)[idx] = v;
        }
      }
    }
  }
}

// FUSED gemm2+gemm3: x2 = relu([mh|x1] @ W2 + b2) ; out = [x1|x2] @ W3 + b3.
// x1 A-fragments (a[r][4..7]) are reused directly as the head's x1 A-operand
// (identical lane layout). x2 is transposed C->A layout through the dead Wt2
// LDS region: XOR-swizzled chunk addressing (phys = row*128 +
// ((chunk^row&15)<<3) + off) gives conflict-free ds_read_b128 on the A-frag
// reads. Wt3 B-fragments stream from global (64KB, L2-broadcast all blocks).
__global__ __launch_bounds__(256, 2) void gemm23_kernel(
    const f16* __restrict__ U,      // mh = mean(x1)
    const f16* __restrict__ V,      // x1h
    const f16* __restrict__ Wt2, const f16* __restrict__ Wt3,
    const float* __restrict__ b2, const float* __restrict__ b3,
    float* __restrict__ out, int M) {
  __shared__ f16 ldsb[32768];   // 64 KB: phase1 = Wt2 stage, phase2 = x2 tile (lower 32KB)
  int tid = threadIdx.x;
  int wave = tid >> 6, lane = tid & 63;
  int quad = lane >> 4, n15 = lane & 15;
  int m0 = blockIdx.x * 128 + wave * 32;
  int kq = quad * 8;

  f16x8 a[2][8];
#pragma unroll
  for (int r = 0; r < 2; ++r) {
    int row = m0 + r * 16 + n15;
    int rowc = row < M ? row : M - 1;
    const f16* bu = U + (size_t)rowc * 128 + kq;
    const f16* bv = V + (size_t)rowc * 128 + kq;
#pragma unroll
    for (int kk = 0; kk < 4; ++kk) a[r][kk] = *(const f16x8*)(bu + kk * 32);
#pragma unroll
    for (int kk = 4; kk < 8; ++kk) a[r][kk] = *(const f16x8*)(bv + (kk - 4) * 32);
  }

#pragma unroll
  for (int it = 0; it < 16; ++it) {
    int idx = it * 256 + tid;
    ((f16x8*)ldsb)[idx] = ((const f16x8*)Wt2)[idx];
  }
  __syncthreads();

  // ---- layer 2 MFMA: acc = [U|V] @ W2
  f32x4 acc[2][8] = {};
#pragma unroll
  for (int kk = 0; kk < 8; ++kk) {
#pragma unroll
    for (int t = 0; t < 8; ++t) {
      f16x8 b = ((const f16x8*)ldsb)[(kk * 4 + quad) * 128 + t * 16 + n15];
#pragma unroll
      for (int r = 0; r < 2; ++r)
        acc[r][t] = __builtin_amdgcn_mfma_f32_16x16x32_f16(a[r][kk], b, acc[r][t], 0, 0, 0);
    }
  }

  __syncthreads();   // all waves done reading Wt2 from LDS

  // ---- write relu(x2)+b2 as f16 into XOR-swizzled LDS tile [128][128]
#pragma unroll
  for (int t = 0; t < 8; ++t) {
    float bv = b2[t * 16 + n15];
    int chunk = t * 2 + (n15 >> 3);
    int offc = n15 & 7;
#pragma unroll
    for (int r = 0; r < 2; ++r) {
#pragma unroll
      for (int i = 0; i < 4; ++i) {
        int rowl = wave * 32 + r * 16 + quad * 4 + i;
        float v = fmaxf(acc[r][t][i] + bv, 0.f);
        ldsb[rowl * 128 + (((chunk ^ (rowl & 15)) << 3) | offc)] = (f16)v;
      }
    }
  }
  __syncthreads();

  // ---- head: out = x1 @ W3_top + x2 @ W3_bot + b3
  f16x8 a2[2][4];
#pragma unroll
  for (int r = 0; r < 2; ++r) {
    int rowl = wave * 32 + r * 16 + n15;
#pragma unroll
    for (int kk2 = 0; kk2 < 4; ++kk2) {
      int chunk = kk2 * 4 + quad;
      a2[r][kk2] = *(const f16x8*)(ldsb + rowl * 128 + ((chunk ^ (rowl & 15)) << 3));
    }
  }

  f32x4 acc3[2][8] = {};
#pragma unroll
  for (int kk = 0; kk < 8; ++kk) {
#pragma unroll
    for (int t = 0; t < 8; ++t) {
      f16x8 b = ((const f16x8*)Wt3)[(kk * 4 + quad) * 128 + t * 16 + n15];
#pragma unroll
      for (int r = 0; r < 2; ++r) {
        f16x8 av = (kk < 4) ? a[r][4 + kk] : a2[r][kk - 4];
        acc3[r][t] = __builtin_amdgcn_mfma_f32_16x16x32_f16(av, b, acc3[r][t], 0, 0, 0);
      }
    }
  }

  int rbase0 = m0 + quad * 4;
#pragma unroll
  for (int t = 0; t < 8; ++t) {
    float bv = b3[t * 16 + n15];
#pragma unroll
    for (int r = 0; r < 2; ++r) {
#pragma unroll
      for (int i = 0; i < 4; ++i) {
        int row = rbase0 + r * 16 + i;
        if (row < M)
          out[(size_t)row * 128 + t * 16 + n15] = acc3[r][t][i] + bv;
      }
    }
  }
}

extern "C" void kernel_launch(void* const* d_in, const int* in_sizes, int n_in,
                              void* d_out, int out_size, void* d_ws, size_t ws_size,
                              hipStream_t stream) {
  (void)n_in; (void)out_size; (void)ws_size;
  const float* x    = (const float*)d_in[0];
  const int*   ei   = (const int*)d_in[1];
  const float* W1l  = (const float*)d_in[2];
  const float* b1l  = (const float*)d_in[3];
  const float* W1r  = (const float*)d_in[4];
  const float* W2l  = (const float*)d_in[5];
  const float* b2l  = (const float*)d_in[6];
  const float* W2r  = (const float*)d_in[7];
  const float* Wlin = (const float*)d_in[8];
  const float* blin = (const float*)d_in[9];
  const int N = in_sizes[0] / 128;
  const int E = in_sizes[1] / 2;

  char* ws = (char*)d_ws;
  size_t o = 0;
  auto alloc = [&](size_t bytes) {
    char* p = ws + o;
    o = (o + bytes + 255) & ~(size_t)255;
    return p;
  };
  f16*  xh   = (f16*)alloc((size_t)N * 128 * 2);
  f16*  x1h  = (f16*)alloc((size_t)N * 128 * 2);
  f16*  mh   = (f16*)alloc((size_t)N * 128 * 2);
  f16*  wt   = (f16*)alloc((size_t)3 * 32768 * 2);   // wt1|wt2|wt3 contiguous
  int*  off  = (int*)alloc(((size_t)N + 1) * 4);
  int*  srcs = (int*)alloc((size_t)E * 4);
  u32*  tmp  = (u32*)alloc((size_t)E * 4);           // packed (src<<8)|dstLow
  int*  ghist= (int*)alloc(256 * RNB * 4);
  f16* wt1 = wt, *wt2 = wt + 32768, *wt3 = wt + 65536;

  const int n4 = N * 128 / 4;
  const int cb = (n4 + 255) / 256;           // convert blocks
  const int wb = (3 * 32768) / 256;          // weight blocks (384)
  const int HB = (N + 255) / 256;            // high-byte buckets (196)

  // prep (convert + weights + radix hist)
  prep_kernel<<<cb + wb + RNB, 256, 0, stream>>>(x, xh, n4, ei, ghist, E,
                                                 W1l, W1r, W2l, W2r, Wlin, wt, cb, wb);
  // CSR build (atomic-free; global prefix rebuilt inline — no scan kernel)
  radix_scatter<<<RNB, 256, 0, stream>>>(ei, ghist, tmp, E);
  radix_bucket<<<HB, 256, 0, stream>>>(tmp, ghist, srcs, off, N, E, HB);

  const int aggBlocks  = ((N + 1) / 2 + 3) / 4;   // 2 nodes/wave, 4 waves/block
  const int gemmBlocks = (N + 127) / 128;         // 128 rows/block

  // layer 1: x1 = relu(mean(x) @ W1_l + x @ W1_r + b1)
  aggregate_kernel<<<aggBlocks, 256, 0, stream>>>(xh, off, srcs, mh, N);
  gemm_kernel<true, true><<<gemmBlocks, 256, 0, stream>>>(mh, xh, wt1, b1l, x1h, N);
  // layer 2 + head fused: x2 = relu(mean(x1) @ W2 + b2); out = [x1|x2] @ W3 + b3
  aggregate_kernel<<<aggBlocks, 256, 0, stream>>>(x1h, off, srcs, mh, N);
  gemm23_kernel<<<gemmBlocks, 256, 0, stream>>>(mh, x1h, wt2, wt3, b2l, blin,
                                                (float*)d_out, N);
}

// Round 2
// 225.939 us; speedup vs baseline: 1.0137x; 1.0137x over previous
//
#include <hip/hip_runtime.h>

// GraphSAGE 2-layer + linear head, N=50000, E=600000, C=128 everywhere.
// R11: fix R10's regression-in-the-fusion: gemm23's head read Wt3 B-frags
//      from GLOBAL inside the MFMA loop (64 x dwordx4/thread ~ 100MB L2 +
//      exposed latency). Now Wt3 is staged through LDS in two 32KB halves,
//      reusing the Wt2 buffer as each half dies:
//        stage Wt2 | L2-MFMA(upper chunks) | stage Wt3top->upper ||
//        L2-MFMA(lower) | x2->lower (swizzled) | head1(x1 regs x Wt3top) |
//        stage Wt3bot->upper | head2(x2 LDS x Wt3bot).
//      B-read pattern identical to measured-good gemm v2. +2 barriers.
// R10 ledger: fusion+scan-fold NEUTRAL (+2.3) — predicted -20. Root cause
//      attributed to unstaged Wt3 (this round tests that attribution).
// R9 ledger (keep): slice-agg REGRESSED vs R3 prefetch-all agg; ILP-depth
//      neutral, fp8 neutral, XCD-slice negative. v2 64KB gemm beats col-split.

typedef _Float16 f16;
typedef unsigned int u32;
typedef __attribute__((ext_vector_type(4))) _Float16 f16x4;
typedef __attribute__((ext_vector_type(8))) _Float16 f16x8;
typedef __attribute__((ext_vector_type(4))) float f32x4;

#define RNB 128   // radix blocks (256 bins x 128 = 32768 hist entries)

// ---- prep: [0,cb) convert x -> f16 | [cb,cb+wb) weights | rest: radix hist
// weights k-chunked transposed, 3 tables contiguous (32768 f16 each):
// wt[w][(chunk*128 + n)*8 + j] = W_w[k=chunk*8+j][n], W = [WA;WB] stacked.
__global__ void prep_kernel(const float* __restrict__ x, f16* __restrict__ xh, int n4,
                            const int* __restrict__ ei, int* __restrict__ ghist, int E,
                            const float* __restrict__ W1l, const float* __restrict__ W1r,
                            const float* __restrict__ W2l, const float* __restrict__ W2r,
                            const float* __restrict__ Wlin, f16* __restrict__ wt,
                            int cb, int wb) {
  int b = blockIdx.x;
  if (b < cb) {
    int i = b * 256 + threadIdx.x;
    if (i < n4) {
      const float4 v = ((const float4*)x)[i];
      f16x4 h = { (f16)v.x, (f16)v.y, (f16)v.z, (f16)v.w };
      ((f16x4*)xh)[i] = h;
    }
  } else if (b < cb + wb) {
    int tid = (b - cb) * 256 + threadIdx.x;   // 0 .. 3*32768
    int w = tid >> 15, idx = tid & 32767;
    int j = idx & 7, n = (idx >> 3) & 127, chunk = idx >> 10;
    int k = chunk * 8 + j;
    float v;
    if (w == 0) v = (k < 128) ? W1l[k * 128 + n] : W1r[(k - 128) * 128 + n];
    else if (w == 1) v = (k < 128) ? W2l[k * 128 + n] : W2r[(k - 128) * 128 + n];
    else v = Wlin[k * 128 + n];
    wt[tid] = (f16)v;
  } else {
    __shared__ int h[256];
    int tid = threadIdx.x, rb = b - cb - wb;   // 0..RNB-1
    h[tid] = 0;
    __syncthreads();
    int per = (E + RNB - 1) / RNB;
    int s = rb * per, e = s + per; if (e > E) e = E;
    for (int i = s + tid; i < e; i += 256) atomicAdd(&h[ei[E + i] >> 8], 1);
    __syncthreads();
    ghist[tid * RNB + rb] = h[tid];
  }
}

// shfl-based exclusive scan over 256 threads (4 waves); one barrier.
// returns exclusive prefix of v; ws must be __shared__ int[4].
__device__ inline int block_excl_scan256(int v, int* ws) {
  int lane = threadIdx.x & 63, w = threadIdx.x >> 6;
  int incl = v;
#pragma unroll
  for (int o = 1; o < 64; o <<= 1) {
    int u = __shfl_up(incl, o);
    if (lane >= o) incl += u;
  }
  if (lane == 63) ws[w] = incl;
  __syncthreads();
  int base = 0;
#pragma unroll
  for (int i = 0; i < 4; ++i) base += (i < w) ? ws[i] : 0;
  return base + incl - v;
}

// deterministic scatter into per-(block,bin) ranges; LDS cursors only.
// Global prefix rebuilt inline from ghist (row-sum + 256-scan) — no scan kernel.
// tmp entry = (src<<8) | (dst & 255)  -- 32-bit, requires src < 2^24.
__global__ void radix_scatter(const int* __restrict__ ei, const int* __restrict__ ghist,
                              u32* __restrict__ tmp, int E) {
  __shared__ int cur[256];
  __shared__ int ws[4];
  int tid = threadIdx.x, b = blockIdx.x;
  const int* row = ghist + tid * RNB;
  int part = 0, rest = 0;
  for (int i = 0; i < b; ++i) part += row[i];          // entries of my bin in blocks < b
  for (int i = b; i < RNB; ++i) rest += row[i];
  int total = part + rest;
  int excl = block_excl_scan256(total, ws);            // entries of bins < mine
  cur[tid] = excl + part;
  __syncthreads();
  int per = (E + RNB - 1) / RNB;
  int s = b * per, e = s + per; if (e > E) e = E;
  for (int i = s + tid; i < e; i += 256) {
    int d = ei[E + i], sr = ei[i];
    int pos = atomicAdd(&cur[d >> 8], 1);              // LDS atomic
    tmp[pos] = ((u32)sr << 8) | (u32)(d & 255);
  }
}

// one block per high-byte bucket: LDS low-byte hist + scan -> off[] + srcs.
__global__ void radix_bucket(const u32* __restrict__ tmp, const int* __restrict__ ghist,
                             int* __restrict__ srcs, int* __restrict__ off,
                             int N, int E, int HB) {
  __shared__ int h[256], sc[256], cur[256];
  __shared__ int bsc[257];
  __shared__ int ws[4];
  int tid = threadIdx.x, hb = blockIdx.x;
  // rebuild global per-bin prefix from ghist
  const int* row = ghist + tid * RNB;
  int total = 0;
#pragma unroll 4
  for (int i = 0; i < RNB; ++i) total += row[i];
  int excl = block_excl_scan256(total, ws);
  bsc[tid] = excl;
  if (tid == 255) bsc[256] = E;
  h[tid] = 0;
  __syncthreads();
  int start = bsc[hb];
  int end = bsc[hb + 1];
  for (int i = start + tid; i < end; i += 256) atomicAdd(&h[tmp[i] & 255u], 1);
  __syncthreads();
  sc[tid] = h[tid];
  __syncthreads();
  for (int o = 1; o < 256; o <<= 1) {
    int u = (tid >= o) ? sc[tid - o] : 0;
    __syncthreads();
    sc[tid] += u;
    __syncthreads();
  }
  int exclb = sc[tid] - h[tid];
  int v = (hb << 8) + tid;
  if (v < N) off[v] = start + exclb;
  if (hb == 0 && tid == 0) off[N] = E;
  cur[tid] = start + exclb;
  __syncthreads();
  for (int i = start + tid; i < end; i += 256) {
    u32 p = tmp[i];
    int pos = atomicAdd(&cur[p & 255u], 1);   // LDS atomic
    srcs[pos] = (int)(p >> 8);
  }
}

// agg v3 (R3, best measured): wave = 2 nodes; lane = slot(sub) x chgroup(n15).
// Prefetch up to 24 edge indices/node, then all gathers, single drain,
// fp32 accum, cross-slot shfl reduce, f16 mean out.
#define AGG_R 6
__global__ void aggregate_kernel(const f16* __restrict__ feat, const int* __restrict__ off,
                                 const int* __restrict__ srcs, f16* __restrict__ meanf, int n) {
  int pair = (int)((blockIdx.x * blockDim.x + threadIdx.x) >> 6);
  int w0 = pair * 2;
  if (w0 >= n) return;
  int w1 = w0 + 1;
  int lane = threadIdx.x & 63;
  int sub = lane >> 4, n15 = lane & 15;
  int beg0 = off[w0], end0 = off[w0 + 1];
  int beg1 = end0;                              // CSR contiguity
  int end1 = (w1 < n) ? off[w1 + 1] : end0;
  int deg0 = end0 - beg0, deg1 = end1 - beg1;

  int s0[AGG_R], s1[AGG_R];
  bool v0[AGG_R], v1[AGG_R];
#pragma unroll
  for (int k = 0; k < AGG_R; ++k) {
    int p = 4 * k + sub;
    v0[k] = p < deg0;  s0[k] = v0[k] ? srcs[beg0 + p] : 0;
    v1[k] = p < deg1;  s1[k] = v1[k] ? srcs[beg1 + p] : 0;
  }
  f16x8 g0[AGG_R], g1[AGG_R];
#pragma unroll
  for (int k = 0; k < AGG_R; ++k) {
    if (v0[k]) g0[k] = *(const f16x8*)(feat + (size_t)s0[k] * 128 + n15 * 8);
    if (v1[k]) g1[k] = *(const f16x8*)(feat + (size_t)s1[k] * 128 + n15 * 8);
  }
  float acc0[8] = {}, acc1[8] = {};
#pragma unroll
  for (int k = 0; k < AGG_R; ++k) {
    if (v0[k]) {
#pragma unroll
      for (int j = 0; j < 8; ++j) acc0[j] += (float)g0[k][j];
    }
    if (v1[k]) {
#pragma unroll
      for (int j = 0; j < 8; ++j) acc1[j] += (float)g1[k][j];
    }
  }
  for (int e = beg0 + 4 * AGG_R; e < end0; e += 4) {   // rare deg>24 tail
    if (sub < end0 - e) {
      int s = srcs[e + sub];
      f16x8 g = *(const f16x8*)(feat + (size_t)s * 128 + n15 * 8);
#pragma unroll
      for (int j = 0; j < 8; ++j) acc0[j] += (float)g[j];
    }
  }
  for (int e = beg1 + 4 * AGG_R; e < end1; e += 4) {
    if (sub < end1 - e) {
      int s = srcs[e + sub];
      f16x8 g = *(const f16x8*)(feat + (size_t)s * 128 + n15 * 8);
#pragma unroll
      for (int j = 0; j < 8; ++j) acc1[j] += (float)g[j];
    }
  }
#pragma unroll
  for (int j = 0; j < 8; ++j) {
    acc0[j] += __shfl_xor(acc0[j], 16);
    acc0[j] += __shfl_xor(acc0[j], 32);
    acc1[j] += __shfl_xor(acc1[j], 16);
    acc1[j] += __shfl_xor(acc1[j], 32);
  }
  if (sub == 0) {
    float inv = 1.0f / fmaxf((float)deg0, 1.0f);
    f16x8 o;
#pragma unroll
    for (int j = 0; j < 8; ++j) o[j] = (f16)(acc0[j] * inv);
    *(f16x8*)(meanf + (size_t)w0 * 128 + n15 * 8) = o;
  } else if (sub == 1 && w1 < n) {
    float inv = 1.0f / fmaxf((float)deg1, 1.0f);
    f16x8 o;
#pragma unroll
    for (int j = 0; j < 8; ++j) o[j] = (f16)(acc1[j] * inv);
    *(f16x8*)(meanf + (size_t)w1 * 128 + n15 * 8) = o;
  }
}

// GEMM v2 (best measured, layer 1): Y[M,128] = act([U|V][M,256] @ W + bias);
// Wt k-chunked in 64KB LDS; 4 waves; wave = 32 rows x 128 cols.
template <bool RELU, bool OUT16>
__global__ __launch_bounds__(256, 2) void gemm_kernel(
    const f16* __restrict__ U, const f16* __restrict__ V, const f16* __restrict__ Wt,
    const float* __restrict__ bias, void* __restrict__ outp, int M) {
  __shared__ f16 ldsb[32768];   // 64 KB
  int tid = threadIdx.x;
  int wave = tid >> 6, lane = tid & 63;
  int quad = lane >> 4, n15 = lane & 15;
  int m0 = blockIdx.x * 128 + wave * 32;
  int kq = quad * 8;

  f16x8 a[2][8];
#pragma unroll
  for (int r = 0; r < 2; ++r) {
    int row = m0 + r * 16 + n15;
    int rowc = row < M ? row : M - 1;   // clamp tail loads (stores guarded)
    const f16* bu = U + (size_t)rowc * 128 + kq;
    const f16* bv = V + (size_t)rowc * 128 + kq;
#pragma unroll
    for (int kk = 0; kk < 4; ++kk) a[r][kk] = *(const f16x8*)(bu + kk * 32);
#pragma unroll
    for (int kk = 4; kk < 8; ++kk) a[r][kk] = *(const f16x8*)(bv + (kk - 4) * 32);
  }

#pragma unroll
  for (int it = 0; it < 16; ++it) {
    int idx = it * 256 + tid;
    ((f16x8*)ldsb)[idx] = ((const f16x8*)Wt)[idx];
  }
  __syncthreads();

  f32x4 acc[2][8] = {};
#pragma unroll
  for (int kk = 0; kk < 8; ++kk) {
#pragma unroll
    for (int t = 0; t < 8; ++t) {
      f16x8 b = ((const f16x8*)ldsb)[(kk * 4 + quad) * 128 + t * 16 + n15];
#pragma unroll
      for (int r = 0; r < 2; ++r)
        acc[r][t] = __builtin_amdgcn_mfma_f32_16x16x32_f16(a[r][kk], b, acc[r][t], 0, 0, 0);
    }
  }

  int rbase0 = m0 + quad * 4;
#pragma unroll
  for (int t = 0; t < 8; ++t) {
    float bv = bias[t * 16 + n15];
#pragma unroll
    for (int r = 0; r < 2; ++r) {
#pragma unroll
      for (int i = 0; i < 4; ++i) {
        int row = rbase0 + r * 16 + i;
        if (row < M) {
          float v = acc[r][t][i] + bv;
          if (RELU) v = fmaxf(v, 0.f);
          size_t idx = (size_t)row * 128 + t * 16 + n15;
          if (OUT16) ((f16*)outp)[idx] = (f16)v;
          else       ((float*)outp)[idx] = v;
        }
      }
    }
  }
}

// FUSED gemm2+gemm3: x2 = relu([mh|x1] @ W2 + b2) ; out = [x1|x2] @ W3 + b3.
// x1 A-fragments (a[r][4..7]) reused in-register for the head. x2 never
// round-trips through global: C->A transpose via XOR-swizzled 32KB LDS tile.
// R11: Wt3 staged through LDS in two 32KB halves (upper buffer), with the
// top-half stage overlapped against the lower-chunk layer-2 MFMAs.
__global__ __launch_bounds__(256, 2) void gemm23_kernel(
    const f16* __restrict__ U,      // mh = mean(x1)
    const f16* __restrict__ V,      // x1h
    const f16* __restrict__ Wt2, const f16* __restrict__ Wt3,
    const float* __restrict__ b2, const float* __restrict__ b3,
    float* __restrict__ out, int M) {
  __shared__ f16 ldsb[32768];   // 64 KB; lower 32KB: Wt2lo -> x2 tile,
                                //         upper 32KB: Wt2hi -> Wt3top -> Wt3bot
  int tid = threadIdx.x;
  int wave = tid >> 6, lane = tid & 63;
  int quad = lane >> 4, n15 = lane & 15;
  int m0 = blockIdx.x * 128 + wave * 32;
  int kq = quad * 8;

  f16x8 a[2][8];
#pragma unroll
  for (int r = 0; r < 2; ++r) {
    int row = m0 + r * 16 + n15;
    int rowc = row < M ? row : M - 1;
    const f16* bu = U + (size_t)rowc * 128 + kq;
    const f16* bv = V + (size_t)rowc * 128 + kq;
#pragma unroll
    for (int kk = 0; kk < 4; ++kk) a[r][kk] = *(const f16x8*)(bu + kk * 32);
#pragma unroll
    for (int kk = 4; kk < 8; ++kk) a[r][kk] = *(const f16x8*)(bv + (kk - 4) * 32);
  }

#pragma unroll
  for (int it = 0; it < 16; ++it) {
    int idx = it * 256 + tid;
    ((f16x8*)ldsb)[idx] = ((const f16x8*)Wt2)[idx];
  }
  __syncthreads();

  // ---- layer 2 MFMA, UPPER chunks first (kk=4..7 -> chunks 16..31)
  f32x4 acc[2][8] = {};
#pragma unroll
  for (int kk = 4; kk < 8; ++kk) {
#pragma unroll
    for (int t = 0; t < 8; ++t) {
      f16x8 b = ((const f16x8*)ldsb)[(kk * 4 + quad) * 128 + t * 16 + n15];
#pragma unroll
      for (int r = 0; r < 2; ++r)
        acc[r][t] = __builtin_amdgcn_mfma_f32_16x16x32_f16(a[r][kk], b, acc[r][t], 0, 0, 0);
    }
  }
  __syncthreads();   // upper 32KB free

  // stage Wt3 TOP half into upper 32KB; overlaps with lower-chunk MFMAs below
#pragma unroll
  for (int it = 0; it < 8; ++it) {
    int idx = it * 256 + tid;
    ((f16x8*)ldsb)[2048 + idx] = ((const f16x8*)Wt3)[idx];
  }
  // ---- layer 2 MFMA, LOWER chunks (kk=0..3)
#pragma unroll
  for (int kk = 0; kk < 4; ++kk) {
#pragma unroll
    for (int t = 0; t < 8; ++t) {
      f16x8 b = ((const f16x8*)ldsb)[(kk * 4 + quad) * 128 + t * 16 + n15];
#pragma unroll
      for (int r = 0; r < 2; ++r)
        acc[r][t] = __builtin_amdgcn_mfma_f32_16x16x32_f16(a[r][kk], b, acc[r][t], 0, 0, 0);
    }
  }
  __syncthreads();   // lower 32KB free; Wt3top visible to all waves

  // ---- write relu(x2)+b2 as f16 into XOR-swizzled LDS tile [128][128] (lower)
#pragma unroll
  for (int t = 0; t < 8; ++t) {
    float bv = b2[t * 16 + n15];
    int chunk = t * 2 + (n15 >> 3);
    int offc = n15 & 7;
#pragma unroll
    for (int r = 0; r < 2; ++r) {
#pragma unroll
      for (int i = 0; i < 4; ++i) {
        int rowl = wave * 32 + r * 16 + quad * 4 + i;
        float v = fmaxf(acc[r][t][i] + bv, 0.f);
        ldsb[rowl * 128 + (((chunk ^ (rowl & 15)) << 3) | offc)] = (f16)v;
      }
    }
  }
  __syncthreads();

  // ---- read x2 A-frags from lower (conflict-free b128 via swizzle)
  f16x8 a2[2][4];
#pragma unroll
  for (int r = 0; r < 2; ++r) {
    int rowl = wave * 32 + r * 16 + n15;
#pragma unroll
    for (int kk2 = 0; kk2 < 4; ++kk2) {
      int chunk = kk2 * 4 + quad;
      a2[r][kk2] = *(const f16x8*)(ldsb + rowl * 128 + ((chunk ^ (rowl & 15)) << 3));
    }
  }

  // ---- head part 1: x1 (regs) x Wt3top (upper LDS), kk=0..3
  f32x4 acc3[2][8] = {};
#pragma unroll
  for (int kk = 0; kk < 4; ++kk) {
#pragma unroll
    for (int t = 0; t < 8; ++t) {
      f16x8 b = ((const f16x8*)ldsb)[2048 + (kk * 4 + quad) * 128 + t * 16 + n15];
#pragma unroll
      for (int r = 0; r < 2; ++r)
        acc3[r][t] = __builtin_amdgcn_mfma_f32_16x16x32_f16(a[r][4 + kk], b, acc3[r][t], 0, 0, 0);
    }
  }
  __syncthreads();   // upper free again

  // stage Wt3 BOTTOM half into upper 32KB
#pragma unroll
  for (int it = 0; it < 8; ++it) {
    int idx = it * 256 + tid;
    ((f16x8*)ldsb)[2048 + idx] = ((const f16x8*)Wt3)[2048 + idx];
  }
  __syncthreads();

  // ---- head part 2: x2 (LDS lower, in a2) x Wt3bot (upper LDS), kk=4..7
#pragma unroll
  for (int kk = 4; kk < 8; ++kk) {
#pragma unroll
    for (int t = 0; t < 8; ++t) {
      f16x8 b = ((const f16x8*)ldsb)[2048 + ((kk - 4) * 4 + quad) * 128 + t * 16 + n15];
#pragma unroll
      for (int r = 0; r < 2; ++r)
        acc3[r][t] = __builtin_amdgcn_mfma_f32_16x16x32_f16(a2[r][kk - 4], b, acc3[r][t], 0, 0, 0);
    }
  }

  int rbase0 = m0 + quad * 4;
#pragma unroll
  for (int t = 0; t < 8; ++t) {
    float bv = b3[t * 16 + n15];
#pragma unroll
    for (int r = 0; r < 2; ++r) {
#pragma unroll
      for (int i = 0; i < 4; ++i) {
        int row = rbase0 + r * 16 + i;
        if (row < M)
          out[(size_t)row * 128 + t * 16 + n15] = acc3[r][t][i] + bv;
      }
    }
  }
}

extern "C" void kernel_launch(void* const* d_in, const int* in_sizes, int n_in,
                              void* d_out, int out_size, void* d_ws, size_t ws_size,
                              hipStream_t stream) {
  (void)n_in; (void)out_size; (void)ws_size;
  const float* x    = (const float*)d_in[0];
  const int*   ei   = (const int*)d_in[1];
  const float* W1l  = (const float*)d_in[2];
  const float* b1l  = (const float*)d_in[3];
  const float* W1r  = (const float*)d_in[4];
  const float* W2l  = (const float*)d_in[5];
  const float* b2l  = (const float*)d_in[6];
  const float* W2r  = (const float*)d_in[7];
  const float* Wlin = (const float*)d_in[8];
  const float* blin = (const float*)d_in[9];
  const int N = in_sizes[0] / 128;
  const int E = in_sizes[1] / 2;

  char* ws = (char*)d_ws;
  size_t o = 0;
  auto alloc = [&](size_t bytes) {
    char* p = ws + o;
    o = (o + bytes + 255) & ~(size_t)255;
    return p;
  };
  f16*  xh   = (f16*)alloc((size_t)N * 128 * 2);
  f16*  x1h  = (f16*)alloc((size_t)N * 128 * 2);
  f16*  mh   = (f16*)alloc((size_t)N * 128 * 2);
  f16*  wt   = (f16*)alloc((size_t)3 * 32768 * 2);   // wt1|wt2|wt3 contiguous
  int*  off  = (int*)alloc(((size_t)N + 1) * 4);
  int*  srcs = (int*)alloc((size_t)E * 4);
  u32*  tmp  = (u32*)alloc((size_t)E * 4);           // packed (src<<8)|dstLow
  int*  ghist= (int*)alloc(256 * RNB * 4);
  f16* wt1 = wt, *wt2 = wt + 32768, *wt3 = wt + 65536;

  const int n4 = N * 128 / 4;
  const int cb = (n4 + 255) / 256;           // convert blocks
  const int wb = (3 * 32768) / 256;          // weight blocks (384)
  const int HB = (N + 255) / 256;            // high-byte buckets (196)

  // prep (convert + weights + radix hist)
  prep_kernel<<<cb + wb + RNB, 256, 0, stream>>>(x, xh, n4, ei, ghist, E,
                                                 W1l, W1r, W2l, W2r, Wlin, wt, cb, wb);
  // CSR build (atomic-free; global prefix rebuilt inline — no scan kernel)
  radix_scatter<<<RNB, 256, 0, stream>>>(ei, ghist, tmp, E);
  radix_bucket<<<HB, 256, 0, stream>>>(tmp, ghist, srcs, off, N, E, HB);

  const int aggBlocks  = ((N + 1) / 2 + 3) / 4;   // 2 nodes/wave, 4 waves/block
  const int gemmBlocks = (N + 127) / 128;         // 128 rows/block

  // layer 1: x1 = relu(mean(x) @ W1_l + x @ W1_r + b1)
  aggregate_kernel<<<aggBlocks, 256, 0, stream>>>(xh, off, srcs, mh, N);
  gemm_kernel<true, true><<<gemmBlocks, 256, 0, stream>>>(mh, xh, wt1, b1l, x1h, N);
  // layer 2 + head fused: x2 = relu(mean(x1) @ W2 + b2); out = [x1|x2] @ W3 + b3
  aggregate_kernel<<<aggBlocks, 256, 0, stream>>>(x1h, off, srcs, mh, N);
  gemm23_kernel<<<gemmBlocks, 256, 0, stream>>>(mh, x1h, wt2, wt3, b2l, blin,
                                                (float*)d_out, N);
}